// Round 1
// 319.390 us; speedup vs baseline: 1.0803x; 1.0803x over previous
//
#include <hip/hip_runtime.h>
#include <stdint.h>
#include <math.h>

// Problem constants (fixed by setup_inputs: B=4, N=4096, H=2048, L=64, K=8)
constexpr int H     = 2048;
constexpr int L     = 64;
constexpr int K_SEL = 8;

// GEMM geometry: 64x64 tile, 1 wave/block, 8x8 per-thread micro-tile,
// K split 8 ways (slab 256) -> grid 2048 = 8 waves/CU = 2 waves/SIMD.
constexpr int TMR   = 64;        // rows per block tile
constexpr int KS    = 8;         // k-split factor
constexpr int KSLAB = H / KS;    // 256
constexpr int BK    = 32;        // k per LDS stage (8 stages/slab)
constexpr int SX    = 68;        // xs[k][row] stride: 68%32=4 -> <=2-way banks (free)
constexpr int SW    = 68;        // wls[k][col] stride

// EPS: fp32 accumulation noise sigma ~3e-6 (split-K pairwise sum + atomic order
// adds ~1e-6). 1e-4 = >30 sigma. Rows whose min adjacent biased-gap over ranks
// 1..9 < EPS get exact fp64 recompute (n_fix ~ 16384*8*EPS/0.071 ~ 185 rows).
constexpr float EPS_GAP = 1e-4f;

// ws layout (4-byte units)
constexpr int WS_COUNTS = 0;        // uint[65]: per-expert counts + [64]=active rows
constexpr int WS_NFIX   = 128;      // uint: fixup-row count
constexpr int WS_LIST   = 256;      // uint[16384]: fixup row indices
constexpr int WS_WT     = 16640;    // float[2048*64]: W transposed for coalesced fixup
constexpr int WS_LOGITS = 147712;   // float[16384*64]: fp32 logits accumulator (4 MiB)

// ---------------------------------------------------------------- prep ----
// blocks [0,32): transpose W -> Wt via LDS tile; block 32: zero counters;
// blocks [33,97): zero the 4 MiB logits accumulator.
__global__ __launch_bounds__(256)
void prep(const float* __restrict__ Wr, float* __restrict__ Wt,
          unsigned int* __restrict__ wsu, float* __restrict__ logits)
{
    const int t = threadIdx.x, b = blockIdx.x;
    if (b == 32) {
        if (t < L + 1) wsu[WS_COUNTS + t] = 0u;
        if (t == 0)    wsu[WS_NFIX] = 0u;
        return;
    }
    if (b >= 33) {   // 64 blocks x 256 thr x 16 float4 = 1,048,576 floats
        float4* p = (float4*)logits;
        const int zb = b - 33;
        #pragma unroll
        for (int q = 0; q < 16; ++q)
            p[(size_t)zb * 4096 + q * 256 + t] = make_float4(0.f, 0.f, 0.f, 0.f);
        return;
    }
    __shared__ float tile[64 * 65];
    const int k0 = b * 64;
    {
        const int l = t >> 2, kq = (t & 3) * 16;
        #pragma unroll
        for (int j = 0; j < 4; ++j) {
            float4 v = *(const float4*)(Wr + (size_t)l * H + k0 + kq + 4 * j);
            int k = kq + 4 * j;
            tile[(k + 0) * 65 + l] = v.x;
            tile[(k + 1) * 65 + l] = v.y;
            tile[(k + 2) * 65 + l] = v.z;
            tile[(k + 3) * 65 + l] = v.w;
        }
    }
    __syncthreads();
    {
        const int k = t >> 2, lq = (t & 3) * 16;
        #pragma unroll
        for (int j = 0; j < 4; ++j) {
            int l2 = lq + 4 * j;
            float4 o = make_float4(tile[k * 65 + l2], tile[k * 65 + l2 + 1],
                                   tile[k * 65 + l2 + 2], tile[k * 65 + l2 + 3]);
            *(float4*)(Wt + (size_t)(k0 + k) * L + l2) = o;
        }
    }
}

// ---------------------------------------------------------------- gemm ----
// Split-K fp32 GEMM: block = 1 wave (64 thr), tile 64 rows x 64 cols x 256 k.
// Per-thread 8x8 accumulator -> LDS reads 1 B/FMA (was 2 with 4x4 tiles).
// Partials combined by fp32 atomicAdd into the logits accumulator.
__global__ __launch_bounds__(64, 2)
void router_gemm(const float* __restrict__ x, const float* __restrict__ Wr,
                 float* __restrict__ logits)
{
    __shared__ __align__(16) float smem[2 * BK * SX];  // xs | wls; reused as lg[64][65]
    float* xs  = smem;
    float* wls = smem + BK * SX;

    const int t  = threadIdx.x;
    const int rb = blockIdx.x & 255;   // 256 row blocks
    const int ks = blockIdx.x >> 8;    // 8 k-slabs
    const int R0 = rb * TMR;
    const int k0 = ks * KSLAB;

    const int r0 = 8 * (t >> 3);       // 8 row-octets
    const int c0 = 8 * (t & 7);        // 8 col-octets
    const int u  = t >> 2;             // staging row/col base (0..15)
    const int a  = t & 3;              // staging k-quad select

    float acc[8][8] = {};
    float4 xg[8], wg[8];

    const float* xp = x  + (size_t)(R0 + u) * H + k0 + 4 * a;
    const float* wp = Wr + (size_t)u * H        + k0 + 4 * a;

    // prefetch stage 0: rows/cols u+16j, k-quads 4a+16m
    #pragma unroll
    for (int j = 0; j < 4; ++j)
        #pragma unroll
        for (int m = 0; m < 2; ++m) {
            xg[2 * j + m] = *(const float4*)(xp + (size_t)(16 * j) * H + 16 * m);
            wg[2 * j + m] = *(const float4*)(wp + (size_t)(16 * j) * H + 16 * m);
        }

    for (int s = 0; s < KSLAB / BK; ++s) {
        // stage into LDS (transposed scalar writes: 2-way banks, free)
        #pragma unroll
        for (int j = 0; j < 4; ++j)
            #pragma unroll
            for (int m = 0; m < 2; ++m) {
                const float4 vx = xg[2 * j + m], vw = wg[2 * j + m];
                const int k = 4 * a + 16 * m, rc = u + 16 * j;
                xs [(k + 0) * SX + rc] = vx.x;
                xs [(k + 1) * SX + rc] = vx.y;
                xs [(k + 2) * SX + rc] = vx.z;
                xs [(k + 3) * SX + rc] = vx.w;
                wls[(k + 0) * SW + rc] = vw.x;
                wls[(k + 1) * SW + rc] = vw.y;
                wls[(k + 2) * SW + rc] = vw.z;
                wls[(k + 3) * SW + rc] = vw.w;
            }
        __syncthreads();

        // prefetch next stage (hidden under the fma loop)
        if (s + 1 < KSLAB / BK) {
            const int kb = BK * (s + 1);
            #pragma unroll
            for (int j = 0; j < 4; ++j)
                #pragma unroll
                for (int m = 0; m < 2; ++m) {
                    xg[2 * j + m] = *(const float4*)(xp + (size_t)(16 * j) * H + kb + 16 * m);
                    wg[2 * j + m] = *(const float4*)(wp + (size_t)(16 * j) * H + kb + 16 * m);
                }
        }

        #pragma unroll 8
        for (int kk = 0; kk < BK; ++kk) {
            const float4 xv0 = *(const float4*)(xs  + kk * SX + r0);
            const float4 xv1 = *(const float4*)(xs  + kk * SX + r0 + 4);
            const float4 wv0 = *(const float4*)(wls + kk * SW + c0);
            const float4 wv1 = *(const float4*)(wls + kk * SW + c0 + 4);
            const float xr[8] = {xv0.x, xv0.y, xv0.z, xv0.w, xv1.x, xv1.y, xv1.z, xv1.w};
            const float wc[8] = {wv0.x, wv0.y, wv0.z, wv0.w, wv1.x, wv1.y, wv1.z, wv1.w};
            #pragma unroll
            for (int i = 0; i < 8; ++i)
                #pragma unroll
                for (int j = 0; j < 8; ++j)
                    acc[i][j] = fmaf(xr[i], wc[j], acc[i][j]);
        }
        __syncthreads();
    }

    // park tile in LDS, then coalesced atomic accumulate (256B per wave-inst)
    float* lg = smem;   // [64][65] = 4160 <= 4352 floats
    #pragma unroll
    for (int i = 0; i < 8; ++i)
        #pragma unroll
        for (int j = 0; j < 8; ++j)
            lg[(r0 + i) * 65 + c0 + j] = acc[i][j];
    __syncthreads();

    float* dst = logits + (size_t)R0 * L + t;
    #pragma unroll 8
    for (int i = 0; i < TMR; ++i)
        atomicAdd(dst + (size_t)i * L, lg[i * 65 + t]);
}

// ---------------------------------------------------------------- topk ----
// One wave per 64 rows: stage logits, per-row serial top-9 + gap-gated fixup
// list + softmax + per-block count histogram (same logic as before).
constexpr int TE = 64;
__global__ __launch_bounds__(64)
void router_topk(const float* __restrict__ logits, const float* __restrict__ bias,
                 const unsigned char* __restrict__ am,
                 float* __restrict__ out_sel, float* __restrict__ out_probs,
                 unsigned int* __restrict__ g_counts, unsigned int* __restrict__ nfix,
                 unsigned int* __restrict__ list)
{
    __shared__ float lg[TE][L + 1];
    __shared__ float bs[L];
    __shared__ unsigned int cnt[L + 1];

    const int t  = threadIdx.x;
    const int R0 = blockIdx.x * TE;

    bs[t]  = bias[t];
    cnt[t] = 0;
    if (t == 0) cnt[L] = 0;

    const float4* src = (const float4*)(logits + (size_t)R0 * L);
    #pragma unroll
    for (int q = 0; q < 16; ++q) {
        const int idx = t + 64 * q;          // 1024 float4 = 64 rows x 64 cols
        const float4 v = src[idx];
        const int row = idx >> 4;
        const int c   = (idx & 15) * 4;
        lg[row][c + 0] = v.x;
        lg[row][c + 1] = v.y;
        lg[row][c + 2] = v.z;
        lg[row][c + 3] = v.w;
    }
    __syncthreads();

    {
        const int grow = R0 + t;
        unsigned long long chosen = 0ull;
        int idx[K_SEL];
        float prev = 0.f, gmin = INFINITY;
        for (int kk = 0; kk < K_SEL + 1; ++kk) {   // 9 rounds: need gap rank8->rank9
            float best = -INFINITY; int bi = 0;
            for (int l = 0; l < L; ++l) {
                if ((chosen >> l) & 1ull) continue;
                float v = lg[t][l] + bs[l];        // strict '>' == jax top_k tie-break
                if (v > best) { best = v; bi = l; }
            }
            if (kk > 0) gmin = fminf(gmin, prev - best);
            prev = best;
            if (kk < K_SEL) { chosen |= 1ull << bi; idx[kk] = bi; }
        }

        if (gmin < EPS_GAP) {
            unsigned int p = atomicAdd(nfix, 1u);
            list[p] = (unsigned int)grow;
        } else {
            float zv[K_SEL], mx = -INFINITY;
            #pragma unroll
            for (int kk = 0; kk < K_SEL; ++kk) { zv[kk] = lg[t][idx[kk]]; mx = fmaxf(mx, zv[kk]); }
            float e[K_SEL], ssum = 0.f;
            #pragma unroll
            for (int kk = 0; kk < K_SEL; ++kk) { e[kk] = expf(zv[kk] - mx); ssum += e[kk]; }
            #pragma unroll
            for (int kk = 0; kk < K_SEL; ++kk) {
                out_sel[(size_t)grow * K_SEL + kk]   = (float)idx[kk];
                out_probs[(size_t)grow * K_SEL + kk] = e[kk] / ssum;
            }
            if (am[grow]) {
                atomicAdd(&cnt[L], 1u);
                #pragma unroll
                for (int kk = 0; kk < K_SEL; ++kk) atomicAdd(&cnt[idx[kk]], 1u);
            }
        }
    }
    __syncthreads();
    if (cnt[t]) atomicAdd(&g_counts[t], cnt[t]);
    if (t == 0 && cnt[L]) atomicAdd(&g_counts[L], cnt[L]);
}

// --------------------------------------------------------------- fixup ----
// wave-per-row exact fp64 recompute; 1024 waves >> n_fix (~200) -> <=1 row/wave.
__global__ __launch_bounds__(256)
void fixup(const float* __restrict__ x, const float* __restrict__ Wt,
           const float* __restrict__ bias, const unsigned char* __restrict__ am,
           const unsigned int* __restrict__ nfix, const unsigned int* __restrict__ list,
           float* __restrict__ out_sel, float* __restrict__ out_probs,
           unsigned int* __restrict__ g_counts)
{
    const int lane = threadIdx.x & 63;
    const int wid  = (blockIdx.x << 2) | (threadIdx.x >> 6);
    const int nw   = gridDim.x << 2;
    const int n    = (int)*nfix;
    const double bl = (double)bias[lane];

    for (int i = wid; i < n; i += nw) {
        const int row = (int)list[i];
        const float* xr = x + (size_t)row * H;
        double a0 = 0.0, a1 = 0.0, a2 = 0.0, a3 = 0.0;
        #pragma unroll 2
        for (int k = 0; k < H; k += 16) {
            float4 x0 = *(const float4*)(xr + k);
            float4 x1 = *(const float4*)(xr + k + 4);
            float4 x2 = *(const float4*)(xr + k + 8);
            float4 x3 = *(const float4*)(xr + k + 12);
            a0 = fma((double)x0.x, (double)Wt[(k +  0) * L + lane], a0);
            a1 = fma((double)x0.y, (double)Wt[(k +  1) * L + lane], a1);
            a2 = fma((double)x0.z, (double)Wt[(k +  2) * L + lane], a2);
            a3 = fma((double)x0.w, (double)Wt[(k +  3) * L + lane], a3);
            a0 = fma((double)x1.x, (double)Wt[(k +  4) * L + lane], a0);
            a1 = fma((double)x1.y, (double)Wt[(k +  5) * L + lane], a1);
            a2 = fma((double)x1.z, (double)Wt[(k +  6) * L + lane], a2);
            a3 = fma((double)x1.w, (double)Wt[(k +  7) * L + lane], a3);
            a0 = fma((double)x2.x, (double)Wt[(k +  8) * L + lane], a0);
            a1 = fma((double)x2.y, (double)Wt[(k +  9) * L + lane], a1);
            a2 = fma((double)x2.z, (double)Wt[(k + 10) * L + lane], a2);
            a3 = fma((double)x2.w, (double)Wt[(k + 11) * L + lane], a3);
            a0 = fma((double)x3.x, (double)Wt[(k + 12) * L + lane], a0);
            a1 = fma((double)x3.y, (double)Wt[(k + 13) * L + lane], a1);
            a2 = fma((double)x3.z, (double)Wt[(k + 14) * L + lane], a2);
            a3 = fma((double)x3.w, (double)Wt[(k + 15) * L + lane], a3);
        }
        double acc = (a0 + a1) + (a2 + a3);

        double v = acc + bl;
        int    widx[K_SEL];
        double wlog[K_SEL];
        #pragma unroll
        for (int kk = 0; kk < K_SEL; ++kk) {
            double mv = v; int mi = lane;
            #pragma unroll
            for (int off = 32; off; off >>= 1) {
                double ov = __shfl_xor(mv, off);
                int    oi = __shfl_xor(mi, off);
                if (ov > mv || (ov == mv && oi < mi)) { mv = ov; mi = oi; }
            }
            widx[kk] = mi;
            wlog[kk] = __shfl(acc, mi);
            if (lane == mi) v = -INFINITY;
        }

        double mx = -INFINITY;
        #pragma unroll
        for (int kk = 0; kk < K_SEL; ++kk) mx = fmax(mx, wlog[kk]);
        float e[K_SEL], ssum = 0.f;
        #pragma unroll
        for (int kk = 0; kk < K_SEL; ++kk) { e[kk] = expf((float)(wlog[kk] - mx)); ssum += e[kk]; }

        if (lane < K_SEL) {
            out_sel[(size_t)row * K_SEL + lane]   = (float)widx[lane];
            out_probs[(size_t)row * K_SEL + lane] = e[lane] / ssum;
        }
        if (am[row]) {
            if (lane < K_SEL)  atomicAdd(&g_counts[widx[lane]], 1u);
            if (lane == K_SEL) atomicAdd(&g_counts[L], 1u);
        }
    }
}

// ------------------------------------------------------------ finalize ----
__global__ void router_finalize(const unsigned int* __restrict__ g_counts,
                                float* __restrict__ out_scalars)
{
    const int l = threadIdx.x;  // one wave
    const float denom = (float)g_counts[L] * (float)K_SEL;
    const float f = (float)g_counts[l] / denom;
    float d  = f - 1.0f / (float)L;
    float sq = d * d;
    #pragma unroll
    for (int o = 32; o > 0; o >>= 1) {
        sq += __shfl_down(sq, o);
        d = fmaxf(d, __shfl_down(d, o));
    }
    if (l == 0) {
        out_scalars[0] = (float)L * sq;  // load_balance_loss
        out_scalars[1] = (float)L * d;   // max_vio
    }
}

extern "C" void kernel_launch(void* const* d_in, const int* in_sizes, int n_in,
                              void* d_out, int out_size, void* d_ws, size_t ws_size,
                              hipStream_t stream)
{
    const float* x          = (const float*)d_in[0];
    const float* Wr         = (const float*)d_in[1];
    const float* bias       = (const float*)d_in[2];
    const unsigned char* am = (const unsigned char*)d_in[3];
    float* out = (float*)d_out;
    float* wsf = (float*)d_ws;
    unsigned int* wsu = (unsigned int*)d_ws;

    const int rows = in_sizes[3];  // B*N = 16384

    float* out_sel   = out;
    float* out_probs = out + (size_t)rows * K_SEL;
    float* out_scal  = out + (size_t)rows * K_SEL * 2;

    hipLaunchKernelGGL(prep,            dim3(97),              dim3(256), 0, stream,
                       Wr, wsf + WS_WT, wsu, wsf + WS_LOGITS);
    hipLaunchKernelGGL(router_gemm,     dim3((rows / TMR) * KS), dim3(64), 0, stream,
                       x, Wr, wsf + WS_LOGITS);
    hipLaunchKernelGGL(router_topk,     dim3(rows / TE),       dim3(64),  0, stream,
                       wsf + WS_LOGITS, bias, am, out_sel, out_probs,
                       wsu + WS_COUNTS, wsu + WS_NFIX, wsu + WS_LIST);
    hipLaunchKernelGGL(fixup,           dim3(256),             dim3(256), 0, stream,
                       x, wsf + WS_WT, bias, am, wsu + WS_NFIX, wsu + WS_LIST,
                       out_sel, out_probs, wsu + WS_COUNTS);
    hipLaunchKernelGGL(router_finalize, dim3(1),               dim3(64),  0, stream,
                       wsu + WS_COUNTS, out_scal);
}

// Round 4
// 296.873 us; speedup vs baseline: 1.1623x; 1.0758x over previous
//
#include <hip/hip_runtime.h>
#include <stdint.h>
#include <math.h>

// Problem constants (fixed by setup_inputs: B=4, N=4096, H=2048, L=64, K=8)
constexpr int H     = 2048;
constexpr int L     = 64;
constexpr int K_SEL = 8;

// GEMM geometry: 256x64 tile, 256 thr (4 waves), 8x8 micro-tile (1 B/FMA LDS),
// K split 8 ways -> grid 512 = 2 blocks/CU (8 waves/CU), blocks hide each
// other's barrier drains. All staging writes/reads <=2-way banks.
constexpr int TMR   = 256;       // rows per block tile
constexpr int KS    = 8;         // k-split factor
constexpr int KSLAB = H / KS;    // 256
constexpr int BK    = 32;        // k per LDS stage (8 stages/slab)
constexpr int SXR   = 260;       // xs[k][row] stride (mult of 4 for b128 align)
constexpr int SWR   = 68;        // ws[k][col] stride

// EPS: fp32 accumulation noise sigma ~3e-6 (256-k serial chains + random-order
// 8-way atomic merge -- same structure as the passing round-1 kernel).
// 1e-4 = >30 sigma; flagged rows (~200) get exact fp64 recompute.
constexpr float EPS_GAP = 1e-4f;

// ws layout (4-byte units) -- identical to round-1 (passed; ws_size sufficient)
constexpr int WS_COUNTS = 0;        // uint[65]: per-expert counts + [64]=active rows
constexpr int WS_NFIX   = 128;      // uint: fixup-row count
constexpr int WS_LIST   = 256;      // uint[16384]: fixup row indices
constexpr int WS_WT     = 16640;    // float[2048*64]: W transposed for coalesced fixup
constexpr int WS_LOGITS = 147712;   // float[16384*64]: fp32 logits accumulator (4 MiB)

// ---------------------------------------------------------------- prep ----
// blocks [0,32): transpose W -> Wt via LDS tile; block 32: zero counters;
// blocks [33,97): zero the 4 MiB logits accumulator. (verbatim round-1)
__global__ __launch_bounds__(256)
void prep(const float* __restrict__ Wr, float* __restrict__ Wt,
          unsigned int* __restrict__ wsu, float* __restrict__ logits)
{
    const int t = threadIdx.x, b = blockIdx.x;
    if (b == 32) {
        if (t < L + 1) wsu[WS_COUNTS + t] = 0u;
        if (t == 0)    wsu[WS_NFIX] = 0u;
        return;
    }
    if (b >= 33) {   // 64 blocks x 256 thr x 16 float4 = 1,048,576 floats
        float4* p = (float4*)logits;
        const int zb = b - 33;
        #pragma unroll
        for (int q = 0; q < 16; ++q)
            p[(size_t)zb * 4096 + q * 256 + t] = make_float4(0.f, 0.f, 0.f, 0.f);
        return;
    }
    __shared__ float tile[64 * 65];
    const int k0 = b * 64;
    {
        const int l = t >> 2, kq = (t & 3) * 16;
        #pragma unroll
        for (int j = 0; j < 4; ++j) {
            float4 v = *(const float4*)(Wr + (size_t)l * H + k0 + kq + 4 * j);
            int k = kq + 4 * j;
            tile[(k + 0) * 65 + l] = v.x;
            tile[(k + 1) * 65 + l] = v.y;
            tile[(k + 2) * 65 + l] = v.z;
            tile[(k + 3) * 65 + l] = v.w;
        }
    }
    __syncthreads();
    {
        const int k = t >> 2, lq = (t & 3) * 16;
        #pragma unroll
        for (int j = 0; j < 4; ++j) {
            int l2 = lq + 4 * j;
            float4 o = make_float4(tile[k * 65 + l2], tile[k * 65 + l2 + 1],
                                   tile[k * 65 + l2 + 2], tile[k * 65 + l2 + 3]);
            *(float4*)(Wt + (size_t)(k0 + k) * L + l2) = o;
        }
    }
}

// ---------------------------------------------------------------- gemm ----
__global__ __launch_bounds__(256, 2)
void router_gemm(const float* __restrict__ x, const float* __restrict__ Wr,
                 float* __restrict__ logits)
{
    __shared__ __align__(16) float xs[BK * SXR];   // 33,280 B
    __shared__ __align__(16) float ws[BK * SWR];   //  8,704 B
    __shared__ __align__(16) float lg[64 * 65];    // 16,640 B  (total 58.6 KB)

    const int t   = threadIdx.x;
    const int rb  = blockIdx.x & 63;    // 64 row tiles
    const int ks  = blockIdx.x >> 6;    // 8 k-slabs
    const int R0  = rb * TMR;
    const int k0  = ks * KSLAB;
    const int g   = t >> 3;             // 32 row-octets
    const int j   = t & 7;              // 8 col-octets
    const int r0  = 8 * g, c0 = 8 * j;
    const int wid = t >> 6;             // wave id 0..3
    const int lane = t & 63;

    float acc[8][8] = {};
    float4 xg[8], wg[2];

    // x: thread t stages row R0+t, 32 k per stage (8 float4, within-row).
    // w: wave 'wid' stages k-rows [8*wid, 8*wid+8); lane = col 0..63.
    const float* xp = x  + (size_t)(R0 + t) * H + k0;
    const float* wp = Wr + (size_t)lane * H     + k0 + 8 * wid;

    // prefetch stage 0
    #pragma unroll
    for (int q = 0; q < 8; ++q) xg[q] = *(const float4*)(xp + 4 * q);
    wg[0] = *(const float4*)(wp);
    wg[1] = *(const float4*)(wp + 4);

    for (int s = 0; s < KSLAB / BK; ++s) {
        // stage: xs writes = consecutive lanes -> conflict-free; ws = same
        #pragma unroll
        for (int q = 0; q < 8; ++q) {
            const float4 v = xg[q];
            xs[(4 * q + 0) * SXR + t] = v.x;
            xs[(4 * q + 1) * SXR + t] = v.y;
            xs[(4 * q + 2) * SXR + t] = v.z;
            xs[(4 * q + 3) * SXR + t] = v.w;
        }
        #pragma unroll
        for (int e = 0; e < 2; ++e) {
            const float4 v = wg[e];
            const int kw = 8 * wid + 4 * e;
            ws[(kw + 0) * SWR + lane] = v.x;
            ws[(kw + 1) * SWR + lane] = v.y;
            ws[(kw + 2) * SWR + lane] = v.z;
            ws[(kw + 3) * SWR + lane] = v.w;
        }
        __syncthreads();

        // prefetch next stage (hidden under the fma loop)
        if (s + 1 < KSLAB / BK) {
            const int kb = BK * (s + 1);
            #pragma unroll
            for (int q = 0; q < 8; ++q) xg[q] = *(const float4*)(xp + kb + 4 * q);
            wg[0] = *(const float4*)(wp + kb);
            wg[1] = *(const float4*)(wp + kb + 4);
        }

        #pragma unroll 8
        for (int kk = 0; kk < BK; ++kk) {
            const float4 xv0 = *(const float4*)(xs + kk * SXR + r0);
            const float4 xv1 = *(const float4*)(xs + kk * SXR + r0 + 4);
            const float4 wv0 = *(const float4*)(ws + kk * SWR + c0);
            const float4 wv1 = *(const float4*)(ws + kk * SWR + c0 + 4);
            const float xr[8] = {xv0.x, xv0.y, xv0.z, xv0.w, xv1.x, xv1.y, xv1.z, xv1.w};
            const float wc[8] = {wv0.x, wv0.y, wv0.z, wv0.w, wv1.x, wv1.y, wv1.z, wv1.w};
            #pragma unroll
            for (int i = 0; i < 8; ++i)
                #pragma unroll
                for (int jj = 0; jj < 8; ++jj)
                    acc[i][jj] = fmaf(xr[i], wc[jj], acc[i][jj]);
        }
        __syncthreads();
    }

    // park+flush in 4 chunks of 64 rows: wave c parks its rows into lg,
    // then all 256 threads flush coalesced atomicAdds (256B/wave-instr).
    for (int c = 0; c < 4; ++c) {
        if (wid == c) {
            const int lr = 8 * (g & 7);
            #pragma unroll
            for (int i = 0; i < 8; ++i)
                #pragma unroll
                for (int jj = 0; jj < 8; ++jj)
                    lg[(lr + i) * 65 + c0 + jj] = acc[i][jj];
        }
        __syncthreads();
        float* dst = logits + (size_t)(R0 + 64 * c) * L;
        #pragma unroll
        for (int p = 0; p < 16; ++p) {
            const int idx = t + 256 * p;          // 4096 = 64 rows x 64 cols
            const int row = idx >> 6, col = idx & 63;
            atomicAdd(dst + (size_t)row * L + col, lg[row * 65 + col]);
        }
        __syncthreads();
    }
}

// ---------------------------------------------------------------- topk ----
// 8 lanes per row: rv in registers, butterfly argmax (min-index tie-break =
// jax top_k), gap-gated fixup flag, softmax over selected raw logits.
constexpr int TKR = 32;   // rows per block (256 thr / 8 lanes-per-row)
__global__ __launch_bounds__(256)
void router_topk(const float* __restrict__ logits, const float* __restrict__ bias,
                 const unsigned char* __restrict__ am,
                 float* __restrict__ out_sel, float* __restrict__ out_probs,
                 unsigned int* __restrict__ g_counts, unsigned int* __restrict__ nfix,
                 unsigned int* __restrict__ list)
{
    __shared__ float bs[L];
    __shared__ unsigned int cnt[L + 1];

    const int t   = threadIdx.x;
    const int j   = t & 7;                  // lane within row-group
    const int row = blockIdx.x * TKR + (t >> 3);

    if (t < L)     bs[t]  = bias[t];
    if (t < L + 1) cnt[t] = 0;
    __syncthreads();

    float rv[8], lv[8];
    {
        const float* lp = logits + (size_t)row * L + 8 * j;
        const float4 v0 = *(const float4*)(lp);
        const float4 v1 = *(const float4*)(lp + 4);
        rv[0] = v0.x; rv[1] = v0.y; rv[2] = v0.z; rv[3] = v0.w;
        rv[4] = v1.x; rv[5] = v1.y; rv[6] = v1.z; rv[7] = v1.w;
        #pragma unroll
        for (int i = 0; i < 8; ++i) lv[i] = rv[i] + bs[8 * j + i];
    }

    unsigned msk = 0;
    int   selidx[K_SEL];
    float selraw[K_SEL];
    float prev = 0.f, gmin = INFINITY;

    #pragma unroll
    for (int kk = 0; kk < K_SEL + 1; ++kk) {       // 9 rounds: need gap rank8->rank9
        float best = -INFINITY; int bi = 1 << 30; float braw = 0.f;
        #pragma unroll
        for (int i = 0; i < 8; ++i) {
            const bool free_ = !((msk >> i) & 1u);
            if (free_ && lv[i] > best) { best = lv[i]; bi = 8 * j + i; braw = rv[i]; }
        }
        #pragma unroll
        for (int off = 1; off <= 4; off <<= 1) {   // butterfly over 8-lane group
            const float ov  = __shfl_xor(best, off);
            const int   oi  = __shfl_xor(bi,   off);
            const float orw = __shfl_xor(braw, off);
            if (ov > best || (ov == best && oi < bi)) { best = ov; bi = oi; braw = orw; }
        }
        if (kk > 0) gmin = fminf(gmin, prev - best);
        prev = best;
        if (kk < K_SEL) {
            if ((bi >> 3) == j) msk |= 1u << (bi & 7);
            selidx[kk] = bi;
            selraw[kk] = braw;
        }
    }

    if (gmin < EPS_GAP) {
        if (j == 0) {
            unsigned int p = atomicAdd(nfix, 1u);
            list[p] = (unsigned int)row;
        }
    } else {
        float mx = -INFINITY;
        #pragma unroll
        for (int kk = 0; kk < K_SEL; ++kk) mx = fmaxf(mx, selraw[kk]);
        float e[K_SEL], ssum = 0.f;
        #pragma unroll
        for (int kk = 0; kk < K_SEL; ++kk) { e[kk] = expf(selraw[kk] - mx); ssum += e[kk]; }
        float myp = 0.f; int myi = 0;
        #pragma unroll
        for (int kk = 0; kk < K_SEL; ++kk)
            if (kk == j) { myp = e[kk] / ssum; myi = selidx[kk]; }
        out_sel  [(size_t)row * K_SEL + j] = (float)myi;
        out_probs[(size_t)row * K_SEL + j] = myp;
        if (am[row]) {
            atomicAdd(&cnt[myi], 1u);
            if (j == 0) atomicAdd(&cnt[L], 1u);
        }
    }
    __syncthreads();
    if (t < L + 1 && cnt[t]) atomicAdd(&g_counts[t], cnt[t]);
}

// --------------------------------------------------------------- fixup ----
// wave-per-row exact fp64 recompute (verbatim round-1; proven).
__global__ __launch_bounds__(256)
void fixup(const float* __restrict__ x, const float* __restrict__ Wt,
           const float* __restrict__ bias, const unsigned char* __restrict__ am,
           const unsigned int* __restrict__ nfix, const unsigned int* __restrict__ list,
           float* __restrict__ out_sel, float* __restrict__ out_probs,
           unsigned int* __restrict__ g_counts)
{
    const int lane = threadIdx.x & 63;
    const int wid  = (blockIdx.x << 2) | (threadIdx.x >> 6);
    const int nw   = gridDim.x << 2;
    const int n    = (int)*nfix;
    const double bl = (double)bias[lane];

    for (int i = wid; i < n; i += nw) {
        const int row = (int)list[i];
        const float* xr = x + (size_t)row * H;
        double a0 = 0.0, a1 = 0.0, a2 = 0.0, a3 = 0.0;
        #pragma unroll 2
        for (int k = 0; k < H; k += 16) {
            float4 x0 = *(const float4*)(xr + k);
            float4 x1 = *(const float4*)(xr + k + 4);
            float4 x2 = *(const float4*)(xr + k + 8);
            float4 x3 = *(const float4*)(xr + k + 12);
            a0 = fma((double)x0.x, (double)Wt[(k +  0) * L + lane], a0);
            a1 = fma((double)x0.y, (double)Wt[(k +  1) * L + lane], a1);
            a2 = fma((double)x0.z, (double)Wt[(k +  2) * L + lane], a2);
            a3 = fma((double)x0.w, (double)Wt[(k +  3) * L + lane], a3);
            a0 = fma((double)x1.x, (double)Wt[(k +  4) * L + lane], a0);
            a1 = fma((double)x1.y, (double)Wt[(k +  5) * L + lane], a1);
            a2 = fma((double)x1.z, (double)Wt[(k +  6) * L + lane], a2);
            a3 = fma((double)x1.w, (double)Wt[(k +  7) * L + lane], a3);
            a0 = fma((double)x2.x, (double)Wt[(k +  8) * L + lane], a0);
            a1 = fma((double)x2.y, (double)Wt[(k +  9) * L + lane], a1);
            a2 = fma((double)x2.z, (double)Wt[(k + 10) * L + lane], a2);
            a3 = fma((double)x2.w, (double)Wt[(k + 11) * L + lane], a3);
            a0 = fma((double)x3.x, (double)Wt[(k + 12) * L + lane], a0);
            a1 = fma((double)x3.y, (double)Wt[(k + 13) * L + lane], a1);
            a2 = fma((double)x3.z, (double)Wt[(k + 14) * L + lane], a2);
            a3 = fma((double)x3.w, (double)Wt[(k + 15) * L + lane], a3);
        }
        double acc = (a0 + a1) + (a2 + a3);

        double v = acc + bl;
        int    widx[K_SEL];
        double wlog[K_SEL];
        #pragma unroll
        for (int kk = 0; kk < K_SEL; ++kk) {
            double mv = v; int mi = lane;
            #pragma unroll
            for (int off = 32; off; off >>= 1) {
                double ov = __shfl_xor(mv, off);
                int    oi = __shfl_xor(mi, off);
                if (ov > mv || (ov == mv && oi < mi)) { mv = ov; mi = oi; }
            }
            widx[kk] = mi;
            wlog[kk] = __shfl(acc, mi);
            if (lane == mi) v = -INFINITY;
        }

        double mx = -INFINITY;
        #pragma unroll
        for (int kk = 0; kk < K_SEL; ++kk) mx = fmax(mx, wlog[kk]);
        float e[K_SEL], ssum = 0.f;
        #pragma unroll
        for (int kk = 0; kk < K_SEL; ++kk) { e[kk] = expf((float)(wlog[kk] - mx)); ssum += e[kk]; }

        if (lane < K_SEL) {
            out_sel[(size_t)row * K_SEL + lane]   = (float)widx[lane];
            out_probs[(size_t)row * K_SEL + lane] = e[lane] / ssum;
        }
        if (am[row]) {
            if (lane < K_SEL)  atomicAdd(&g_counts[widx[lane]], 1u);
            if (lane == K_SEL) atomicAdd(&g_counts[L], 1u);
        }
    }
}

// ------------------------------------------------------------ finalize ----
__global__ void router_finalize(const unsigned int* __restrict__ g_counts,
                                float* __restrict__ out_scalars)
{
    const int l = threadIdx.x;  // one wave
    const float denom = (float)g_counts[L] * (float)K_SEL;
    const float f = (float)g_counts[l] / denom;
    float d  = f - 1.0f / (float)L;
    float sq = d * d;
    #pragma unroll
    for (int o = 32; o > 0; o >>= 1) {
        sq += __shfl_down(sq, o);
        d = fmaxf(d, __shfl_down(d, o));
    }
    if (l == 0) {
        out_scalars[0] = (float)L * sq;  // load_balance_loss
        out_scalars[1] = (float)L * d;   // max_vio
    }
}

extern "C" void kernel_launch(void* const* d_in, const int* in_sizes, int n_in,
                              void* d_out, int out_size, void* d_ws, size_t ws_size,
                              hipStream_t stream)
{
    const float* x          = (const float*)d_in[0];
    const float* Wr         = (const float*)d_in[1];
    const float* bias       = (const float*)d_in[2];
    const unsigned char* am = (const unsigned char*)d_in[3];
    float* out = (float*)d_out;
    float* wsf = (float*)d_ws;
    unsigned int* wsu = (unsigned int*)d_ws;

    const int rows = in_sizes[3];  // B*N = 16384

    float* out_sel   = out;
    float* out_probs = out + (size_t)rows * K_SEL;
    float* out_scal  = out + (size_t)rows * K_SEL * 2;

    hipLaunchKernelGGL(prep,            dim3(97),                dim3(256), 0, stream,
                       Wr, wsf + WS_WT, wsu, wsf + WS_LOGITS);
    hipLaunchKernelGGL(router_gemm,     dim3((rows / TMR) * KS), dim3(256), 0, stream,
                       x, Wr, wsf + WS_LOGITS);
    hipLaunchKernelGGL(router_topk,     dim3(rows / TKR),        dim3(256), 0, stream,
                       wsf + WS_LOGITS, bias, am, out_sel, out_probs,
                       wsu + WS_COUNTS, wsu + WS_NFIX, wsu + WS_LIST);
    hipLaunchKernelGGL(fixup,           dim3(256),               dim3(256), 0, stream,
                       x, wsf + WS_WT, bias, am, wsu + WS_NFIX, wsu + WS_LIST,
                       out_sel, out_probs, wsu + WS_COUNTS);
    hipLaunchKernelGGL(router_finalize, dim3(1),                 dim3(64),  0, stream,
                       wsu + WS_COUNTS, out_scal);
}

// Round 6
// 281.166 us; speedup vs baseline: 1.2272x; 1.0559x over previous
//
#include <hip/hip_runtime.h>
#include <stdint.h>
#include <math.h>

// Problem constants (fixed by setup_inputs: B=4, N=4096, H=2048, L=64, K=8)
constexpr int H     = 2048;
constexpr int L     = 64;
constexpr int K_SEL = 8;

// Fused MFMA geometry: block = 256 thr (4 waves), 32 rows x 64 experts x full K.
// bf16 hi/lo split: x = hi + lo (lo = x - hi exact), logits = hh + hl + lh via
// 3x mfma_f32_16x16x32_bf16. Dropped lo*lo term <= 2^-18|x||w| -> noise sigma
// ~3e-6 (same scale as the old fp32-chain), so EPS_GAP machinery is unchanged.
constexpr int RPB   = 32;        // rows per block -> grid 512 = 2 blocks/CU
constexpr int BK    = 32;        // k per LDS stage = one MFMA K (64 stages)
constexpr int NSTG  = H / BK;    // 64
constexpr int SP    = 40;        // padded k-stride (bf16 elems): frag reads bank-uniform

// EPS: gap-gate for exact fp64 recompute (~200 rows expected).
constexpr float EPS_GAP = 1e-4f;

// ws layout (4-byte units) -- ~1.1 MB total (was 4.7 MB)
constexpr int WS_COUNTS = 0;         // uint[65]: per-expert counts + [64]=active rows
constexpr int WS_NFIX   = 128;       // uint: fixup-row count
constexpr int WS_LIST   = 256;       // uint[16384]: fixup row indices
constexpr int WS_WT     = 16640;     // float[2048*64]: W^T for coalesced fp64 fixup
constexpr int WS_WHC    = 147712;    // short[64*2048] via 2 words each: W hi bf16, chunked [c][e][32]
constexpr int WS_WLC    = 213248;    // short[64*2048]: W lo bf16, same layout

typedef __attribute__((ext_vector_type(8))) short bf16x8;
typedef __attribute__((ext_vector_type(4))) float f32x4;

// hi = RNE-bf16(x); lo = bf16(x - hi) (truncated; residual <= 2^-17|x|)
__device__ __forceinline__ void cvt_hi_lo(float c, short& h, short& l)
{
    unsigned u  = __float_as_uint(c);
    unsigned hb = (u + 0x7fffu + ((u >> 16) & 1u)) >> 16;
    float hf    = __uint_as_float(hb << 16);
    float lof   = c - hf;                      // exact in fp32
    h = (short)hb;
    l = (short)(__float_as_uint(lof) >> 16);
}

// ---------------------------------------------------------------- prep ----
// blocks [0,32): transpose W -> Wt (fp64 fixup path); block 32: zero counters;
// blocks [33,65): convert W -> chunked bf16 hi/lo [kchunk][expert][32].
__global__ __launch_bounds__(256)
void prep(const float* __restrict__ Wr, float* __restrict__ Wt,
          unsigned int* __restrict__ wsu, short* __restrict__ whc,
          short* __restrict__ wlc)
{
    const int t = threadIdx.x, b = blockIdx.x;
    if (b == 32) {
        if (t < L + 1) wsu[WS_COUNTS + t] = 0u;
        if (t == 0)    wsu[WS_NFIX] = 0u;
        return;
    }
    if (b >= 33) {   // 32 blocks x 2 experts each; 512 float4 per expert
        const int z = b - 33;
        const int e = 2 * z + (t >> 7);
        const int idx = t & 127;
        #pragma unroll
        for (int u = 0; u < 4; ++u) {              // FIX (r5 bug): was u<2 -> only
            const int f4i = idx + 128 * u;         // covered f4i 0..255 (k<1024);
            const int k   = 4 * f4i;               // chunks c>=32 stayed poisoned.
            const float4 v = ((const float4*)(Wr + (size_t)e * H))[f4i];
            short4 hh, ll;
            cvt_hi_lo(v.x, hh.x, ll.x);
            cvt_hi_lo(v.y, hh.y, ll.y);
            cvt_hi_lo(v.z, hh.z, ll.z);
            cvt_hi_lo(v.w, hh.w, ll.w);
            const int c  = k >> 5, kk = k & 31;
            const int di = (c * 64 + e) * 32 + kk;
            *(short4*)(whc + di) = hh;
            *(short4*)(wlc + di) = ll;
        }
        return;
    }
    __shared__ float tile[64 * 65];
    const int k0 = b * 64;
    {
        const int l = t >> 2, kq = (t & 3) * 16;
        #pragma unroll
        for (int j = 0; j < 4; ++j) {
            float4 v = *(const float4*)(Wr + (size_t)l * H + k0 + kq + 4 * j);
            int k = kq + 4 * j;
            tile[(k + 0) * 65 + l] = v.x;
            tile[(k + 1) * 65 + l] = v.y;
            tile[(k + 2) * 65 + l] = v.z;
            tile[(k + 3) * 65 + l] = v.w;
        }
    }
    __syncthreads();
    {
        const int k = t >> 2, lq = (t & 3) * 16;
        #pragma unroll
        for (int j = 0; j < 4; ++j) {
            int l2 = lq + 4 * j;
            float4 o = make_float4(tile[k * 65 + l2], tile[k * 65 + l2 + 1],
                                   tile[k * 65 + l2 + 2], tile[k * 65 + l2 + 3]);
            *(float4*)(Wt + (size_t)(k0 + k) * L + l2) = o;
        }
    }
}

// ---------------------------------------------------------------- main ----
// Fused: stage x (fp32->bf16 hi/lo) + W (precvt bf16) into LDS, 3-product
// MFMA over K, park logits in LDS, 8-lane-per-row top-9 + outputs + counts.
__global__ __launch_bounds__(256, 2)
void router_mfma(const float* __restrict__ x, const short* __restrict__ whc,
                 const short* __restrict__ wlc, const float* __restrict__ bias,
                 const unsigned char* __restrict__ am,
                 float* __restrict__ out_sel, float* __restrict__ out_probs,
                 unsigned int* __restrict__ g_counts, unsigned int* __restrict__ nfix,
                 unsigned int* __restrict__ list)
{
    __shared__ __align__(16) short sxh[2][RPB * SP];   // 2x2560 B
    __shared__ __align__(16) short sxl[2][RPB * SP];
    __shared__ __align__(16) short swh[2][L * SP];     // 2x5120 B
    __shared__ __align__(16) short swl[2][L * SP];
    __shared__ __align__(16) float lg[RPB * 68];       // 8704 B
    __shared__ float bs[L];
    __shared__ unsigned int cnt[L + 1];

    const int t  = threadIdx.x;
    const int R0 = blockIdx.x * RPB;

    if (t < L)     bs[t]  = bias[t];
    if (t < L + 1) cnt[t] = 0;

    // wave/tile decomposition: wave w: rows 16*(w&1), cols 32*(w>>1)+{0,16}
    const int lw  = t & 63, w = t >> 6;
    const int r0l = 16 * (w & 1);
    const int n0  = 32 * (w >> 1);
    const int fr  = lw & 15;          // fragment row/col index
    const int kg  = lw >> 4;          // k-group 0..3
    const int kb  = 8 * kg;           // k-base within chunk

    // staging addresses: x: thread t stages row t>>3, k-quad 4*(t&7)
    const float*  xp  = x + (size_t)(R0 + (t >> 3)) * H + 4 * (t & 7);
    const float4* whp = (const float4*)whc + t;    // stage slice = 256 float4
    const float4* wlp = (const float4*)wlc + t;

    f32x4 acc[2] = {};
    float4 xg, wh_r, wl_r;

    // stage 0: load + write
    xg   = *(const float4*)(xp);
    wh_r = whp[0];
    wl_r = wlp[0];
    {
        short4 h4, l4;
        cvt_hi_lo(xg.x, h4.x, l4.x);
        cvt_hi_lo(xg.y, h4.y, l4.y);
        cvt_hi_lo(xg.z, h4.z, l4.z);
        cvt_hi_lo(xg.w, h4.w, l4.w);
        const int xi = (t >> 3) * SP + 4 * (t & 7);
        *(short4*)&sxh[0][xi] = h4;
        *(short4*)&sxl[0][xi] = l4;
        const int wi = (t >> 2) * SP + 8 * (t & 3);
        *(float4*)&swh[0][wi] = wh_r;
        *(float4*)&swl[0][wi] = wl_r;
    }
    __syncthreads();
    // preload stage 1 regs
    xg   = *(const float4*)(xp + BK);
    wh_r = whp[256];
    wl_r = wlp[256];

    for (int s = 0; s < NSTG; ++s) {
        const int p = s & 1;
        // write stage s+1 (regs loaded last iter) into buffer p^1
        if (s + 1 < NSTG) {
            short4 h4, l4;
            cvt_hi_lo(xg.x, h4.x, l4.x);
            cvt_hi_lo(xg.y, h4.y, l4.y);
            cvt_hi_lo(xg.z, h4.z, l4.z);
            cvt_hi_lo(xg.w, h4.w, l4.w);
            const int xi = (t >> 3) * SP + 4 * (t & 7);
            *(short4*)&sxh[p ^ 1][xi] = h4;
            *(short4*)&sxl[p ^ 1][xi] = l4;
            const int wi = (t >> 2) * SP + 8 * (t & 3);
            *(float4*)&swh[p ^ 1][wi] = wh_r;
            *(float4*)&swl[p ^ 1][wi] = wl_r;
        }
        // issue global loads for stage s+2 (hidden under MFMA)
        if (s + 2 < NSTG) {
            xg   = *(const float4*)(xp + BK * (s + 2));
            wh_r = whp[256 * (s + 2)];
            wl_r = wlp[256 * (s + 2)];
        }
        // MFMA on stage s
        {
            const bf16x8 ah = *(const bf16x8*)&sxh[p][(r0l + fr) * SP + kb];
            const bf16x8 al = *(const bf16x8*)&sxl[p][(r0l + fr) * SP + kb];
            #pragma unroll
            for (int tt = 0; tt < 2; ++tt) {
                const int nc = (n0 + 16 * tt + fr) * SP + kb;
                const bf16x8 bh = *(const bf16x8*)&swh[p][nc];
                const bf16x8 bl = *(const bf16x8*)&swl[p][nc];
                acc[tt] = __builtin_amdgcn_mfma_f32_16x16x32_bf16(ah, bh, acc[tt], 0, 0, 0);
                acc[tt] = __builtin_amdgcn_mfma_f32_16x16x32_bf16(ah, bl, acc[tt], 0, 0, 0);
                acc[tt] = __builtin_amdgcn_mfma_f32_16x16x32_bf16(al, bh, acc[tt], 0, 0, 0);
            }
        }
        __syncthreads();
    }

    // park logits: D layout col=lane&15, row=4*(lane>>4)+reg  [m89-verified]
    #pragma unroll
    for (int tt = 0; tt < 2; ++tt)
        #pragma unroll
        for (int r = 0; r < 4; ++r)
            lg[(r0l + 4 * kg + r) * 68 + n0 + 16 * tt + fr] = acc[tt][r];
    __syncthreads();

    // ---- top-9 epilogue: 8 lanes per row (proven round-4 structure)
    {
        const int tj   = t & 7;
        const int lrow = t >> 3;             // 0..31
        const int grow = R0 + lrow;

        float rv[8], lv[8];
        {
            const float* lp = &lg[lrow * 68 + 8 * tj];
            const float4 v0 = *(const float4*)(lp);
            const float4 v1 = *(const float4*)(lp + 4);
            rv[0] = v0.x; rv[1] = v0.y; rv[2] = v0.z; rv[3] = v0.w;
            rv[4] = v1.x; rv[5] = v1.y; rv[6] = v1.z; rv[7] = v1.w;
            #pragma unroll
            for (int i = 0; i < 8; ++i) lv[i] = rv[i] + bs[8 * tj + i];
        }

        unsigned msk = 0;
        int   selidx[K_SEL];
        float selraw[K_SEL];
        float prev = 0.f, gmin = INFINITY;

        #pragma unroll
        for (int kk = 0; kk < K_SEL + 1; ++kk) {     // 9 rounds: gap rank8->rank9
            float best = -INFINITY; int bi = 1 << 30; float braw = 0.f;
            #pragma unroll
            for (int i = 0; i < 8; ++i) {
                const bool free_ = !((msk >> i) & 1u);
                if (free_ && lv[i] > best) { best = lv[i]; bi = 8 * tj + i; braw = rv[i]; }
            }
            #pragma unroll
            for (int off = 1; off <= 4; off <<= 1) { // butterfly over 8-lane group
                const float ov  = __shfl_xor(best, off);
                const int   oi  = __shfl_xor(bi,   off);
                const float orw = __shfl_xor(braw, off);
                if (ov > best || (ov == best && oi < bi)) { best = ov; bi = oi; braw = orw; }
            }
            if (kk > 0) gmin = fminf(gmin, prev - best);
            prev = best;
            if (kk < K_SEL) {
                if ((bi >> 3) == tj) msk |= 1u << (bi & 7);
                selidx[kk] = bi;
                selraw[kk] = braw;
            }
        }

        if (gmin < EPS_GAP) {
            if (tj == 0) {
                unsigned int pp = atomicAdd(nfix, 1u);
                list[pp] = (unsigned int)grow;
            }
        } else {
            float mx = -INFINITY;
            #pragma unroll
            for (int kk = 0; kk < K_SEL; ++kk) mx = fmaxf(mx, selraw[kk]);
            float e[K_SEL], ssum = 0.f;
            #pragma unroll
            for (int kk = 0; kk < K_SEL; ++kk) { e[kk] = expf(selraw[kk] - mx); ssum += e[kk]; }
            float myp = 0.f; int myi = 0;
            #pragma unroll
            for (int kk = 0; kk < K_SEL; ++kk)
                if (kk == tj) { myp = e[kk] / ssum; myi = selidx[kk]; }
            out_sel  [(size_t)grow * K_SEL + tj] = (float)myi;
            out_probs[(size_t)grow * K_SEL + tj] = myp;
            if (am[grow]) {
                atomicAdd(&cnt[myi], 1u);
                if (tj == 0) atomicAdd(&cnt[L], 1u);
            }
        }
    }
    __syncthreads();
    if (t < L + 1 && cnt[t]) atomicAdd(&g_counts[t], cnt[t]);
}

// --------------------------------------------------------------- fixup ----
// wave-per-row exact fp64 recompute (verbatim; proven).
__global__ __launch_bounds__(256)
void fixup(const float* __restrict__ x, const float* __restrict__ Wt,
           const float* __restrict__ bias, const unsigned char* __restrict__ am,
           const unsigned int* __restrict__ nfix, const unsigned int* __restrict__ list,
           float* __restrict__ out_sel, float* __restrict__ out_probs,
           unsigned int* __restrict__ g_counts)
{
    const int lane = threadIdx.x & 63;
    const int wid  = (blockIdx.x << 2) | (threadIdx.x >> 6);
    const int nw   = gridDim.x << 2;
    const int n    = (int)*nfix;
    const double bl = (double)bias[lane];

    for (int i = wid; i < n; i += nw) {
        const int row = (int)list[i];
        const float* xr = x + (size_t)row * H;
        double a0 = 0.0, a1 = 0.0, a2 = 0.0, a3 = 0.0;
        #pragma unroll 2
        for (int k = 0; k < H; k += 16) {
            float4 x0 = *(const float4*)(xr + k);
            float4 x1 = *(const float4*)(xr + k + 4);
            float4 x2 = *(const float4*)(xr + k + 8);
            float4 x3 = *(const float4*)(xr + k + 12);
            a0 = fma((double)x0.x, (double)Wt[(k +  0) * L + lane], a0);
            a1 = fma((double)x0.y, (double)Wt[(k +  1) * L + lane], a1);
            a2 = fma((double)x0.z, (double)Wt[(k +  2) * L + lane], a2);
            a3 = fma((double)x0.w, (double)Wt[(k +  3) * L + lane], a3);
            a0 = fma((double)x1.x, (double)Wt[(k +  4) * L + lane], a0);
            a1 = fma((double)x1.y, (double)Wt[(k +  5) * L + lane], a1);
            a2 = fma((double)x1.z, (double)Wt[(k +  6) * L + lane], a2);
            a3 = fma((double)x1.w, (double)Wt[(k +  7) * L + lane], a3);
            a0 = fma((double)x2.x, (double)Wt[(k +  8) * L + lane], a0);
            a1 = fma((double)x2.y, (double)Wt[(k +  9) * L + lane], a1);
            a2 = fma((double)x2.z, (double)Wt[(k + 10) * L + lane], a2);
            a3 = fma((double)x2.w, (double)Wt[(k + 11) * L + lane], a3);
            a0 = fma((double)x3.x, (double)Wt[(k + 12) * L + lane], a0);
            a1 = fma((double)x3.y, (double)Wt[(k + 13) * L + lane], a1);
            a2 = fma((double)x3.z, (double)Wt[(k + 14) * L + lane], a2);
            a3 = fma((double)x3.w, (double)Wt[(k + 15) * L + lane], a3);
        }
        double acc = (a0 + a1) + (a2 + a3);

        double v = acc + bl;
        int    widx[K_SEL];
        double wlog[K_SEL];
        #pragma unroll
        for (int kk = 0; kk < K_SEL; ++kk) {
            double mv = v; int mi = lane;
            #pragma unroll
            for (int off = 32; off; off >>= 1) {
                double ov = __shfl_xor(mv, off);
                int    oi = __shfl_xor(mi, off);
                if (ov > mv || (ov == mv && oi < mi)) { mv = ov; mi = oi; }
            }
            widx[kk] = mi;
            wlog[kk] = __shfl(acc, mi);
            if (lane == mi) v = -INFINITY;
        }

        double mx = -INFINITY;
        #pragma unroll
        for (int kk = 0; kk < K_SEL; ++kk) mx = fmax(mx, wlog[kk]);
        float e[K_SEL], ssum = 0.f;
        #pragma unroll
        for (int kk = 0; kk < K_SEL; ++kk) { e[kk] = expf((float)(wlog[kk] - mx)); ssum += e[kk]; }

        if (lane < K_SEL) {
            out_sel[(size_t)row * K_SEL + lane]   = (float)widx[lane];
            out_probs[(size_t)row * K_SEL + lane] = e[lane] / ssum;
        }
        if (am[row]) {
            if (lane < K_SEL)  atomicAdd(&g_counts[widx[lane]], 1u);
            if (lane == K_SEL) atomicAdd(&g_counts[L], 1u);
        }
    }
}

// ------------------------------------------------------------ finalize ----
__global__ void router_finalize(const unsigned int* __restrict__ g_counts,
                                float* __restrict__ out_scalars)
{
    const int l = threadIdx.x;  // one wave
    const float denom = (float)g_counts[L] * (float)K_SEL;
    const float f = (float)g_counts[l] / denom;
    float d  = f - 1.0f / (float)L;
    float sq = d * d;
    #pragma unroll
    for (int o = 32; o > 0; o >>= 1) {
        sq += __shfl_down(sq, o);
        d = fmaxf(d, __shfl_down(d, o));
    }
    if (l == 0) {
        out_scalars[0] = (float)L * sq;  // load_balance_loss
        out_scalars[1] = (float)L * d;   // max_vio
    }
}

extern "C" void kernel_launch(void* const* d_in, const int* in_sizes, int n_in,
                              void* d_out, int out_size, void* d_ws, size_t ws_size,
                              hipStream_t stream)
{
    const float* x          = (const float*)d_in[0];
    const float* Wr         = (const float*)d_in[1];
    const float* bias       = (const float*)d_in[2];
    const unsigned char* am = (const unsigned char*)d_in[3];
    float* out = (float*)d_out;
    float* wsf = (float*)d_ws;
    unsigned int* wsu = (unsigned int*)d_ws;

    const int rows = in_sizes[3];  // B*N = 16384

    float* out_sel   = out;
    float* out_probs = out + (size_t)rows * K_SEL;
    float* out_scal  = out + (size_t)rows * K_SEL * 2;

    short* whc = (short*)(wsu + WS_WHC);
    short* wlc = (short*)(wsu + WS_WLC);

    hipLaunchKernelGGL(prep,            dim3(65),         dim3(256), 0, stream,
                       Wr, wsf + WS_WT, wsu, whc, wlc);
    hipLaunchKernelGGL(router_mfma,     dim3(rows / RPB), dim3(256), 0, stream,
                       x, whc, wlc, bias, am, out_sel, out_probs,
                       wsu + WS_COUNTS, wsu + WS_NFIX, wsu + WS_LIST);
    hipLaunchKernelGGL(fixup,           dim3(256),        dim3(256), 0, stream,
                       x, wsf + WS_WT, bias, am, wsu + WS_NFIX, wsu + WS_LIST,
                       out_sel, out_probs, wsu + WS_COUNTS);
    hipLaunchKernelGGL(router_finalize, dim3(1),          dim3(64),  0, stream,
                       wsu + WS_COUNTS, out_scal);
}

// Round 7
// 270.875 us; speedup vs baseline: 1.2738x; 1.0380x over previous
//
#include <hip/hip_runtime.h>
#include <stdint.h>
#include <math.h>

// Problem constants (fixed by setup_inputs: B=4, N=4096, H=2048, L=64, K=8)
constexpr int H     = 2048;
constexpr int L     = 64;
constexpr int K_SEL = 8;

// Direct-to-register MFMA geometry: block = 256 thr (4 waves), 32 rows x 64
// experts. Wave w owns k-chunks [16w,16w+16) (chunk = 32 k), accumulates its
// partial logits in registers -- NO LDS, NO barriers in the K-loop (r6 lesson:
// 64 barrier-drained LDS stages left every pipe <15% busy). A-frag (row=lane&15,
// k=8*(lane>>4)+e) = 16B slice of an x row; B-frag = 16B slice of chunked
// whc[c][e][32]. 4 partials merge once in LDS at the end.
constexpr int RPB   = 32;        // rows per block -> grid 512 = 2 blocks/CU
constexpr int NCH   = 16;        // k-chunks per wave (64 total / 4 waves)

// EPS: bf16 hi/lo split noise sigma ~3e-6; 1e-4 = >30 sigma. Flagged rows
// (~200) get exact fp64 recompute.
constexpr float EPS_GAP = 1e-4f;

// ws layout (4-byte units)
constexpr int WS_COUNTS = 0;         // uint[65]: per-expert counts + [64]=active rows
constexpr int WS_NFIX   = 128;       // uint: fixup-row count
constexpr int WS_DONE   = 192;       // uint: fixup block done-counter (fused finalize)
constexpr int WS_LIST   = 256;       // uint[16384]: fixup row indices
constexpr int WS_WT     = 16640;     // float[2048*64]: W^T for coalesced fp64 fixup
constexpr int WS_WHC    = 147712;    // short[64*2048]: W hi bf16, chunked [c][e][32]
constexpr int WS_WLC    = 213248;    // short[64*2048]: W lo bf16, same layout

typedef __attribute__((ext_vector_type(8))) short bf16x8;
typedef __attribute__((ext_vector_type(4))) float f32x4;

// hi = RNE-bf16(x); lo = bf16(x - hi) (truncated; residual <= 2^-17|x|)
__device__ __forceinline__ void cvt_hi_lo(float c, short& h, short& l)
{
    unsigned u  = __float_as_uint(c);
    unsigned hb = (u + 0x7fffu + ((u >> 16) & 1u)) >> 16;
    float hf    = __uint_as_float(hb << 16);
    float lof   = c - hf;                      // exact in fp32
    h = (short)hb;
    l = (short)(__float_as_uint(lof) >> 16);
}

__device__ __forceinline__ void cvt8(const float4& u0, const float4& u1,
                                     bf16x8& h, bf16x8& l)
{
    short hh, ll;
    cvt_hi_lo(u0.x, hh, ll); h[0] = hh; l[0] = ll;
    cvt_hi_lo(u0.y, hh, ll); h[1] = hh; l[1] = ll;
    cvt_hi_lo(u0.z, hh, ll); h[2] = hh; l[2] = ll;
    cvt_hi_lo(u0.w, hh, ll); h[3] = hh; l[3] = ll;
    cvt_hi_lo(u1.x, hh, ll); h[4] = hh; l[4] = ll;
    cvt_hi_lo(u1.y, hh, ll); h[5] = hh; l[5] = ll;
    cvt_hi_lo(u1.z, hh, ll); h[6] = hh; l[6] = ll;
    cvt_hi_lo(u1.w, hh, ll); h[7] = hh; l[7] = ll;
}

// 3-product hi/lo MFMA: c += ah*bh + ah*bl + al*bh
__device__ __forceinline__ f32x4 mm3(const bf16x8& ah, const bf16x8& al,
                                     const bf16x8& bh, const bf16x8& bl, f32x4 c)
{
    c = __builtin_amdgcn_mfma_f32_16x16x32_bf16(ah, bh, c, 0, 0, 0);
    c = __builtin_amdgcn_mfma_f32_16x16x32_bf16(ah, bl, c, 0, 0, 0);
    c = __builtin_amdgcn_mfma_f32_16x16x32_bf16(al, bh, c, 0, 0, 0);
    return c;
}

// ---------------------------------------------------------------- prep ----
// blocks [0,32): transpose W -> Wt (fp64 fixup path); block 32: zero counters;
// blocks [33,65): convert W -> chunked bf16 hi/lo [kchunk][expert][32].
__global__ __launch_bounds__(256)
void prep(const float* __restrict__ Wr, float* __restrict__ Wt,
          unsigned int* __restrict__ wsu, short* __restrict__ whc,
          short* __restrict__ wlc)
{
    const int t = threadIdx.x, b = blockIdx.x;
    if (b == 32) {
        if (t < L + 1) wsu[WS_COUNTS + t] = 0u;
        if (t == 0)    wsu[WS_NFIX] = 0u;
        if (t == 1)    wsu[WS_DONE] = 0u;
        return;
    }
    if (b >= 33) {   // 32 blocks x 2 experts each; 512 float4 per expert
        const int z = b - 33;
        const int e = 2 * z + (t >> 7);
        const int idx = t & 127;
        #pragma unroll
        for (int u = 0; u < 4; ++u) {
            const int f4i = idx + 128 * u;         // 0..511
            const int k   = 4 * f4i;
            const float4 v = ((const float4*)(Wr + (size_t)e * H))[f4i];
            short4 hh, ll;
            cvt_hi_lo(v.x, hh.x, ll.x);
            cvt_hi_lo(v.y, hh.y, ll.y);
            cvt_hi_lo(v.z, hh.z, ll.z);
            cvt_hi_lo(v.w, hh.w, ll.w);
            const int c  = k >> 5, kk = k & 31;
            const int di = (c * 64 + e) * 32 + kk;
            *(short4*)(whc + di) = hh;
            *(short4*)(wlc + di) = ll;
        }
        return;
    }
    __shared__ float tile[64 * 65];
    const int k0 = b * 64;
    {
        const int l = t >> 2, kq = (t & 3) * 16;
        #pragma unroll
        for (int j = 0; j < 4; ++j) {
            float4 v = *(const float4*)(Wr + (size_t)l * H + k0 + kq + 4 * j);
            int k = kq + 4 * j;
            tile[(k + 0) * 65 + l] = v.x;
            tile[(k + 1) * 65 + l] = v.y;
            tile[(k + 2) * 65 + l] = v.z;
            tile[(k + 3) * 65 + l] = v.w;
        }
    }
    __syncthreads();
    {
        const int k = t >> 2, lq = (t & 3) * 16;
        #pragma unroll
        for (int j = 0; j < 4; ++j) {
            int l2 = lq + 4 * j;
            float4 o = make_float4(tile[k * 65 + l2], tile[k * 65 + l2 + 1],
                                   tile[k * 65 + l2 + 2], tile[k * 65 + l2 + 3]);
            *(float4*)(Wt + (size_t)(k0 + k) * L + l2) = o;
        }
    }
}

// ---------------------------------------------------------------- main ----
__global__ __launch_bounds__(256, 2)
void router_mfma(const float* __restrict__ x, const short* __restrict__ whc,
                 const short* __restrict__ wlc, const float* __restrict__ bias,
                 const unsigned char* __restrict__ am,
                 float* __restrict__ out_sel, float* __restrict__ out_probs,
                 unsigned int* __restrict__ g_counts, unsigned int* __restrict__ nfix,
                 unsigned int* __restrict__ list)
{
    __shared__ __align__(16) float lg[4 * RPB * 68];   // 34,816 B: 4 wave-partials
    __shared__ float bs[L];
    __shared__ unsigned int cnt[L + 1];

    const int t  = threadIdx.x;
    const int R0 = blockIdx.x * RPB;
    const int w  = t >> 6, l = t & 63;
    const int fr = l & 15;            // fragment row/col index
    const int kg = l >> 4;            // k-group 0..3
    const int kb = 8 * kg;            // k-base within a 32-k chunk

    if (t < L)     bs[t]  = bias[t];
    if (t < L + 1) cnt[t] = 0;

    // 8 named accumulators: acc_<rg><cg>, rg in {0,1} (rows), cg in {0..3} (cols)
    f32x4 acc_00 = {}, acc_01 = {}, acc_02 = {}, acc_03 = {};
    f32x4 acc_10 = {}, acc_11 = {}, acc_12 = {}, acc_13 = {};

    const float* xp0 = x + (size_t)(R0 + fr) * H + kb;        // rg0 row
    const float* xp1 = xp0 + (size_t)16 * H;                  // rg1 row
    const short* whp = whc + fr * 32 + kb;
    const short* wlp = wlc + fr * 32 + kb;

    // wave w covers chunks [16w, 16w+16) -- contiguous 2 KB x-span per row,
    // contiguous 64 KB whc span. No barriers: compiler pipelines freely.
    #pragma unroll
    for (int ci = 0; ci < NCH; ++ci) {
        const int c  = NCH * w + ci;
        const int xo = 32 * c;            // float offset into row
        const int wo = c * 2048;          // short offset into whc/wlc

        const float4 a00 = *(const float4*)(xp0 + xo);
        const float4 a01 = *(const float4*)(xp0 + xo + 4);
        const float4 a10 = *(const float4*)(xp1 + xo);
        const float4 a11 = *(const float4*)(xp1 + xo + 4);

        const bf16x8 bh0 = *(const bf16x8*)(whp + wo);
        const bf16x8 bh1 = *(const bf16x8*)(whp + wo + 512);
        const bf16x8 bh2 = *(const bf16x8*)(whp + wo + 1024);
        const bf16x8 bh3 = *(const bf16x8*)(whp + wo + 1536);
        const bf16x8 bl0 = *(const bf16x8*)(wlp + wo);
        const bf16x8 bl1 = *(const bf16x8*)(wlp + wo + 512);
        const bf16x8 bl2 = *(const bf16x8*)(wlp + wo + 1024);
        const bf16x8 bl3 = *(const bf16x8*)(wlp + wo + 1536);

        bf16x8 ah0, al0, ah1, al1;
        cvt8(a00, a01, ah0, al0);
        cvt8(a10, a11, ah1, al1);

        acc_00 = mm3(ah0, al0, bh0, bl0, acc_00);
        acc_01 = mm3(ah0, al0, bh1, bl1, acc_01);
        acc_02 = mm3(ah0, al0, bh2, bl2, acc_02);
        acc_03 = mm3(ah0, al0, bh3, bl3, acc_03);
        acc_10 = mm3(ah1, al1, bh0, bl0, acc_10);
        acc_11 = mm3(ah1, al1, bh1, bl1, acc_11);
        acc_12 = mm3(ah1, al1, bh2, bl2, acc_12);
        acc_13 = mm3(ah1, al1, bh3, bl3, acc_13);
    }

    // park partials: D layout col=lane&15, row=4*(lane>>4)+reg [m89-verified]
    {
        float* lgw = lg + w * (RPB * 68);
        const int rb = 4 * kg;
        #pragma unroll
        for (int r = 0; r < 4; ++r) {
            lgw[(rb + r)      * 68 + fr     ] = acc_00[r];
            lgw[(rb + r)      * 68 + fr + 16] = acc_01[r];
            lgw[(rb + r)      * 68 + fr + 32] = acc_02[r];
            lgw[(rb + r)      * 68 + fr + 48] = acc_03[r];
            lgw[(rb + r + 16) * 68 + fr     ] = acc_10[r];
            lgw[(rb + r + 16) * 68 + fr + 16] = acc_11[r];
            lgw[(rb + r + 16) * 68 + fr + 32] = acc_12[r];
            lgw[(rb + r + 16) * 68 + fr + 48] = acc_13[r];
        }
    }
    __syncthreads();

    // 4-way merge into lg[0] (2176 floats = 8.5 * 256)
    #pragma unroll
    for (int q = 0; q < 9; ++q) {
        const int p = t + 256 * q;
        if (p < RPB * 68)
            lg[p] = (lg[p] + lg[RPB * 68 + p]) + (lg[2 * RPB * 68 + p] + lg[3 * RPB * 68 + p]);
    }
    __syncthreads();

    // ---- top-9 epilogue: 8 lanes per row (proven r4/r6 structure)
    {
        const int tj   = t & 7;
        const int lrow = t >> 3;             // 0..31
        const int grow = R0 + lrow;

        float rv[8], lv[8];
        {
            const float* lp = &lg[lrow * 68 + 8 * tj];
            const float4 v0 = *(const float4*)(lp);
            const float4 v1 = *(const float4*)(lp + 4);
            rv[0] = v0.x; rv[1] = v0.y; rv[2] = v0.z; rv[3] = v0.w;
            rv[4] = v1.x; rv[5] = v1.y; rv[6] = v1.z; rv[7] = v1.w;
            #pragma unroll
            for (int i = 0; i < 8; ++i) lv[i] = rv[i] + bs[8 * tj + i];
        }

        unsigned msk = 0;
        int   selidx[K_SEL];
        float selraw[K_SEL];
        float prev = 0.f, gmin = INFINITY;

        #pragma unroll
        for (int kk = 0; kk < K_SEL + 1; ++kk) {     // 9 rounds: gap rank8->rank9
            float best = -INFINITY; int bi = 1 << 30; float braw = 0.f;
            #pragma unroll
            for (int i = 0; i < 8; ++i) {
                const bool free_ = !((msk >> i) & 1u);
                if (free_ && lv[i] > best) { best = lv[i]; bi = 8 * tj + i; braw = rv[i]; }
            }
            #pragma unroll
            for (int off = 1; off <= 4; off <<= 1) { // butterfly over 8-lane group
                const float ov  = __shfl_xor(best, off);
                const int   oi  = __shfl_xor(bi,   off);
                const float orw = __shfl_xor(braw, off);
                if (ov > best || (ov == best && oi < bi)) { best = ov; bi = oi; braw = orw; }
            }
            if (kk > 0) gmin = fminf(gmin, prev - best);
            prev = best;
            if (kk < K_SEL) {
                if ((bi >> 3) == tj) msk |= 1u << (bi & 7);
                selidx[kk] = bi;
                selraw[kk] = braw;
            }
        }

        if (gmin < EPS_GAP) {
            if (tj == 0) {
                unsigned int pp = atomicAdd(nfix, 1u);
                list[pp] = (unsigned int)grow;
            }
        } else {
            float mx = -INFINITY;
            #pragma unroll
            for (int kk = 0; kk < K_SEL; ++kk) mx = fmaxf(mx, selraw[kk]);
            float e[K_SEL], ssum = 0.f;
            #pragma unroll
            for (int kk = 0; kk < K_SEL; ++kk) { e[kk] = expf(selraw[kk] - mx); ssum += e[kk]; }
            float myp = 0.f; int myi = 0;
            #pragma unroll
            for (int kk = 0; kk < K_SEL; ++kk)
                if (kk == tj) { myp = e[kk] / ssum; myi = selidx[kk]; }
            out_sel  [(size_t)grow * K_SEL + tj] = (float)myi;
            out_probs[(size_t)grow * K_SEL + tj] = myp;
            if (am[grow]) {
                atomicAdd(&cnt[myi], 1u);
                if (tj == 0) atomicAdd(&cnt[L], 1u);
            }
        }
    }
    __syncthreads();
    if (t < L + 1 && cnt[t]) atomicAdd(&g_counts[t], cnt[t]);
}

// ----------------------------------------------------- fixup + finalize ----
// wave-per-row exact fp64 recompute (proven), then the LAST block (done-
// counter + threadfence + atomic reads) computes the loss scalars.
__global__ __launch_bounds__(256)
void fixup_fin(const float* __restrict__ x, const float* __restrict__ Wt,
               const float* __restrict__ bias, const unsigned char* __restrict__ am,
               const unsigned int* __restrict__ nfix, const unsigned int* __restrict__ list,
               float* __restrict__ out_sel, float* __restrict__ out_probs,
               unsigned int* __restrict__ g_counts, unsigned int* __restrict__ done,
               float* __restrict__ out_scalars)
{
    const int lane = threadIdx.x & 63;
    const int wid  = (blockIdx.x << 2) | (threadIdx.x >> 6);
    const int nw   = gridDim.x << 2;
    const int n    = (int)*nfix;
    const double bl = (double)bias[lane];

    for (int i = wid; i < n; i += nw) {
        const int row = (int)list[i];
        const float* xr = x + (size_t)row * H;
        double a0 = 0.0, a1 = 0.0, a2 = 0.0, a3 = 0.0;
        #pragma unroll 2
        for (int k = 0; k < H; k += 16) {
            float4 x0 = *(const float4*)(xr + k);
            float4 x1 = *(const float4*)(xr + k + 4);
            float4 x2 = *(const float4*)(xr + k + 8);
            float4 x3 = *(const float4*)(xr + k + 12);
            a0 = fma((double)x0.x, (double)Wt[(k +  0) * L + lane], a0);
            a1 = fma((double)x0.y, (double)Wt[(k +  1) * L + lane], a1);
            a2 = fma((double)x0.z, (double)Wt[(k +  2) * L + lane], a2);
            a3 = fma((double)x0.w, (double)Wt[(k +  3) * L + lane], a3);
            a0 = fma((double)x1.x, (double)Wt[(k +  4) * L + lane], a0);
            a1 = fma((double)x1.y, (double)Wt[(k +  5) * L + lane], a1);
            a2 = fma((double)x1.z, (double)Wt[(k +  6) * L + lane], a2);
            a3 = fma((double)x1.w, (double)Wt[(k +  7) * L + lane], a3);
            a0 = fma((double)x2.x, (double)Wt[(k +  8) * L + lane], a0);
            a1 = fma((double)x2.y, (double)Wt[(k +  9) * L + lane], a1);
            a2 = fma((double)x2.z, (double)Wt[(k + 10) * L + lane], a2);
            a3 = fma((double)x2.w, (double)Wt[(k + 11) * L + lane], a3);
            a0 = fma((double)x3.x, (double)Wt[(k + 12) * L + lane], a0);
            a1 = fma((double)x3.y, (double)Wt[(k + 13) * L + lane], a1);
            a2 = fma((double)x3.z, (double)Wt[(k + 14) * L + lane], a2);
            a3 = fma((double)x3.w, (double)Wt[(k + 15) * L + lane], a3);
        }
        double acc = (a0 + a1) + (a2 + a3);

        double v = acc + bl;
        int    widx[K_SEL];
        double wlog[K_SEL];
        #pragma unroll
        for (int kk = 0; kk < K_SEL; ++kk) {
            double mv = v; int mi = lane;
            #pragma unroll
            for (int off = 32; off; off >>= 1) {
                double ov = __shfl_xor(mv, off);
                int    oi = __shfl_xor(mi, off);
                if (ov > mv || (ov == mv && oi < mi)) { mv = ov; mi = oi; }
            }
            widx[kk] = mi;
            wlog[kk] = __shfl(acc, mi);
            if (lane == mi) v = -INFINITY;
        }

        double mx = -INFINITY;
        #pragma unroll
        for (int kk = 0; kk < K_SEL; ++kk) mx = fmax(mx, wlog[kk]);
        float e[K_SEL], ssum = 0.f;
        #pragma unroll
        for (int kk = 0; kk < K_SEL; ++kk) { e[kk] = expf((float)(wlog[kk] - mx)); ssum += e[kk]; }

        if (lane < K_SEL) {
            out_sel[(size_t)row * K_SEL + lane]   = (float)widx[lane];
            out_probs[(size_t)row * K_SEL + lane] = e[lane] / ssum;
        }
        if (am[row]) {
            if (lane < K_SEL)  atomicAdd(&g_counts[widx[lane]], 1u);
            if (lane == K_SEL) atomicAdd(&g_counts[L], 1u);
        }
    }

    // ---- finalize handoff: last block to finish computes the scalars
    __shared__ bool last;
    __syncthreads();
    if (threadIdx.x == 0) {
        __threadfence();                       // publish this block's atomics
        last = (atomicAdd(done, 1u) == (unsigned)gridDim.x - 1u);
    }
    __syncthreads();
    if (!last) return;

    const int l = threadIdx.x;
    if (l < L) {
        const unsigned cl = atomicAdd(&g_counts[l], 0u);   // coherent read
        const unsigned ct = atomicAdd(&g_counts[L], 0u);
        const float denom = (float)ct * (float)K_SEL;
        const float f = (float)cl / denom;
        float d  = f - 1.0f / (float)L;
        float sq = d * d;
        #pragma unroll
        for (int o = 32; o > 0; o >>= 1) {
            sq += __shfl_down(sq, o);
            d = fmaxf(d, __shfl_down(d, o));
        }
        if (l == 0) {
            out_scalars[0] = (float)L * sq;  // load_balance_loss
            out_scalars[1] = (float)L * d;   // max_vio
        }
    }
}

extern "C" void kernel_launch(void* const* d_in, const int* in_sizes, int n_in,
                              void* d_out, int out_size, void* d_ws, size_t ws_size,
                              hipStream_t stream)
{
    const float* x          = (const float*)d_in[0];
    const float* Wr         = (const float*)d_in[1];
    const float* bias       = (const float*)d_in[2];
    const unsigned char* am = (const unsigned char*)d_in[3];
    float* out = (float*)d_out;
    float* wsf = (float*)d_ws;
    unsigned int* wsu = (unsigned int*)d_ws;

    const int rows = in_sizes[3];  // B*N = 16384

    float* out_sel   = out;
    float* out_probs = out + (size_t)rows * K_SEL;
    float* out_scal  = out + (size_t)rows * K_SEL * 2;

    short* whc = (short*)(wsu + WS_WHC);
    short* wlc = (short*)(wsu + WS_WLC);

    hipLaunchKernelGGL(prep,        dim3(65),         dim3(256), 0, stream,
                       Wr, wsf + WS_WT, wsu, whc, wlc);
    hipLaunchKernelGGL(router_mfma, dim3(rows / RPB), dim3(256), 0, stream,
                       x, whc, wlc, bias, am, out_sel, out_probs,
                       wsu + WS_COUNTS, wsu + WS_NFIX, wsu + WS_LIST);
    hipLaunchKernelGGL(fixup_fin,   dim3(256),        dim3(256), 0, stream,
                       x, wsf + WS_WT, bias, am, wsu + WS_NFIX, wsu + WS_LIST,
                       out_sel, out_probs, wsu + WS_COUNTS, wsu + WS_DONE,
                       out_scal);
}